// Round 6
// baseline (124.205 us; speedup 1.0000x reference)
//
#include <hip/hip_runtime.h>
#include <hip/hip_bf16.h>

// out[b,k] = sum_{i,j} x[b,i] * W[k,i,j] * x[b,j]
// GEMM P (B x 160 XOR-classed pair-products) @ Q (160 x 16),
// 5 x mfma_f32_16x16x32_bf16 per 16-row tile.
//
// R11: register-free software pipeline. Facts driving it: absolute VALU
// work invariant ~17.5us across R5/R7/R9/R10; occupancy pinned ~50%
// (~4 waves/SIMD real); ONE load in flight per wave -> latency-bound at
// 2.4 TB/s. Registers are the poisoned resource (R7), so prefetch depth
// must cost ZERO VGPRs:
//   - per-wave 2-slot LDS ring (2 x 1KB); ONE global_load_lds dwordx4 per
//     tile (64 lanes x 16B = whole tile, linear dest = HW constraint);
//   - counted s_waitcnt vmcnt(N) (T3/T4 pattern, per-wave, no barriers —
//     each wave owns its slots). Ledger with exactly 1 load + 1 store per
//     tile (stream L0,L1,[S0,L2]..[S5,L7],[S6],[S7]): wait vmcnt(1) at
//     j=0 and j=7, vmcnt(2) at j=1..6. Requires exactly 8 tiles/wave
//     (65536/8192 — fixed shape); generic fallback otherwise.
//   - the 8 ds_bpermute shuffles die: lanes read chunks q, q^1, q^2 of
//     their row from the LDS tile image (3 x ds_read_b128, bit-identical
//     f32 values).
// Compute/epilogue bit-identical to harness-verified R10: products, 3+2
// dual MFMA chains, AGPR-pinned b-frags, Tb transpose, dwordx4 store.
//
// XOR class algebra unchanged (orbit-enumeration verified): K-slot
// k = 32s+8q+j holds, at lane quad q, x[alpha_c^4q]*x[beta_c^4q], c=8s+j;
// 120 off-diag pairs net weight 1, 16 diagonals once. xv slot s = raw
// chunk s^q of row n.

typedef __attribute__((ext_vector_type(8)))  short  short8;
typedef __attribute__((ext_vector_type(8)))  __bf16 bf16x8;
typedef __attribute__((ext_vector_type(4)))  float  floatx4;

#define DEV static __device__ __forceinline__

// ---- XOR class table ----
constexpr int cA(int c) {            // alpha
    if (c < 24) { const int dIdx = c >> 1, v = c & 1;
        const int hi = dIdx / 3, lo = dIdx % 3 + 1;
        const int base = (hi == 3) ? 1 : 0;
        const int l = v ? ((lo == 1) ? 2 : 1) : 0;
        return base * 4 + l; }
    if (c < 36) { const int g = c - 24, hi = g / 4 + 1, l = g & 3;
        const int base = (hi == 3) ? 1 : 0;
        return base * 4 + l; }
    return c - 36;
}
constexpr int cDd(int c) {           // d = alpha ^ beta
    if (c < 24) { const int dIdx = c >> 1;
        return (dIdx / 3) * 4 + (dIdx % 3 + 1); }
    if (c < 36) { return ((c - 24) / 4 + 1) * 4; }
    return 0;
}
constexpr int   cB(int c) { return cA(c) ^ cDd(c); }
constexpr float cW(int c) { return (c >= 24 && c < 36) ? 0.5f : 1.0f; }

template <int C>
DEV float pval(const float* xv) {    // xv indexed directly by value id (<=11)
    return xv[cA(C)] * xv[cB(C)];
}

template <int S>   // frag S covers classes c = 8S .. 8S+7
DEV short8 make_afrag(const float* xv) {
    union { short8 s; __hip_bfloat162 h[4]; } u;
    u.h[0] = __float22bfloat162_rn(make_float2(pval<8 * S + 0>(xv), pval<8 * S + 1>(xv)));
    u.h[1] = __float22bfloat162_rn(make_float2(pval<8 * S + 2>(xv), pval<8 * S + 3>(xv)));
    u.h[2] = __float22bfloat162_rn(make_float2(pval<8 * S + 4>(xv), pval<8 * S + 5>(xv)));
    u.h[3] = __float22bfloat162_rn(make_float2(pval<8 * S + 6>(xv), pval<8 * S + 7>(xv)));
    return u.s;
}

DEV floatx4 mfma_bf16(short8 a, short8 b, floatx4 c) {
    return __builtin_amdgcn_mfma_f32_16x16x32_bf16(
        __builtin_bit_cast(bf16x8, a), __builtin_bit_cast(bf16x8, b), c, 0, 0, 0);
}

// ---- Q element for flat slot e = n*160 + k,  k = 32s + 8q + j ----
DEV float q_elem(const float* __restrict__ W, int e) {
    const int n = e / 160;
    const int k = e - n * 160;
    const int s = k >> 5, q = (k >> 3) & 3, j = k & 7;
    const int c = 8 * s + j;
    const int I = cA(c) ^ (q << 2);
    const int J = cB(c) ^ (q << 2);
    return (I == J) ? W[n * 256 + I * 16 + I]
                    : cW(c) * (W[n * 256 + I * 16 + J] + W[n * 256 + J * 16 + I]);
}

typedef const __attribute__((address_space(1))) unsigned char* gptr_t;
typedef       __attribute__((address_space(3))) unsigned char* lptr_t;

__global__ __launch_bounds__(256, 8)
void bilinear16_kernel(const float* __restrict__ x, const float* __restrict__ W,
                       float* __restrict__ out, int ntiles) {
    __shared__ __align__(16) short Qt[16][160];     // 5120 B
    __shared__ __align__(16) float Tb[4][320];      // 5120 B
    __shared__ __align__(16) float Ring[4][2][256]; // 8192 B (per-wave 2x1KB)

    const int tid = threadIdx.x;
    for (int e = tid; e < 16 * 160; e += 256) {
        __hip_bfloat16 h = __float2bfloat16(q_elem(W, e));
        Qt[0][e] = *reinterpret_cast<short*>(&h);
    }
    __syncthreads();

    const int lane = tid & 63;
    const int n    = lane & 15;   // MFMA A-row / C col (fixed by HW layout)
    const int q    = lane >> 4;   // MFMA k-group quad
    const int wid  = tid >> 6;
    float* const tb   = Tb[wid];
    float* const ring = &Ring[wid][0][0];

    // B-frags (20 regs), resident, pinned to AGPRs (R10-verified).
    short8 b0 = *reinterpret_cast<const short8*>(&Qt[n][0 * 32 + q * 8]);
    short8 b1 = *reinterpret_cast<const short8*>(&Qt[n][1 * 32 + q * 8]);
    short8 b2 = *reinterpret_cast<const short8*>(&Qt[n][2 * 32 + q * 8]);
    short8 b3 = *reinterpret_cast<const short8*>(&Qt[n][3 * 32 + q * 8]);
    short8 b4 = *reinterpret_cast<const short8*>(&Qt[n][4 * 32 + q * 8]);
    asm("" : "+a"(b0)); asm("" : "+a"(b1)); asm("" : "+a"(b2));
    asm("" : "+a"(b3)); asm("" : "+a"(b4));

    const int waveId = blockIdx.x * 4 + wid;
    const int nwaves = gridDim.x * 4;
    const int n16    = n * 16;

    // Compute+store one tile whose image sits in ring slot `rs` (verified
    // R10 arithmetic; xv values bit-identical — same f32 words).
    auto tile_compute = [&](const float* rs, float* obase) {
        const float4 v0 = *reinterpret_cast<const float4*>(rs + n16 + q * 4);
        const float4 v1 = *reinterpret_cast<const float4*>(rs + n16 + (q ^ 1) * 4);
        const float4 v2 = *reinterpret_cast<const float4*>(rs + n16 + (q ^ 2) * 4);
        const float xv[12] = {v0.x, v0.y, v0.z, v0.w,
                              v1.x, v1.y, v1.z, v1.w,
                              v2.x, v2.y, v2.z, v2.w};
        floatx4 acc0 = {0.f, 0.f, 0.f, 0.f};
        floatx4 acc1 = {0.f, 0.f, 0.f, 0.f};
        acc0 = mfma_bf16(make_afrag<0>(xv), b0, acc0);
        acc1 = mfma_bf16(make_afrag<1>(xv), b1, acc1);
        acc0 = mfma_bf16(make_afrag<2>(xv), b2, acc0);
        acc1 = mfma_bf16(make_afrag<3>(xv), b3, acc1);
        acc0 = mfma_bf16(make_afrag<4>(xv), b4, acc0);
        acc0 = acc0 + acc1;
        // C/D layout: col = lane&15, row = q*4 + reg [m89-verified].
        tb[(q * 4 + 0) * 20 + n] = acc0[0];
        tb[(q * 4 + 1) * 20 + n] = acc0[1];
        tb[(q * 4 + 2) * 20 + n] = acc0[2];
        tb[(q * 4 + 3) * 20 + n] = acc0[3];
        const float4 o = *reinterpret_cast<const float4*>(
            &tb[(lane >> 2) * 20 + (lane & 3) * 4]);
        *reinterpret_cast<float4*>(obase + lane * 4) = o;
    };

#define PREF(J)                                                                 \
    __builtin_amdgcn_global_load_lds(                                           \
        (gptr_t)(const void*)(x + (size_t)(t0 + (J) * nwaves) * 256 + lane * 4),\
        (lptr_t)(void*)(ring + ((J) & 1) * 256), 16, 0, 0)

#define TILE(J, VMC)                                                            \
    do {                                                                        \
        asm volatile("s_waitcnt vmcnt(" #VMC ")" ::: "memory");                 \
        tile_compute(ring + ((J) & 1) * 256,                                    \
                     out + (size_t)(t0 + (J) * nwaves) * 256);                  \
        if ((J) < 6) { asm volatile("" ::: "memory"); PREF((J) + 2); }          \
    } while (0)

    if (ntiles == nwaves * 8) {
        const int t0 = waveId;
        PREF(0); PREF(1);
        TILE(0, 1); TILE(1, 2); TILE(2, 2); TILE(3, 2);
        TILE(4, 2); TILE(5, 2); TILE(6, 2); TILE(7, 1);
    } else {
        // Generic fallback (R10 path: shuffle-based, no pipeline).
        for (int t = waveId; t < ntiles; t += nwaves) {
            const float4 own = *reinterpret_cast<const float4*>(
                x + (size_t)t * 256 + n * 16 + q * 4);
            float4 s1, s2;
            s1.x = __shfl_xor(own.x, 16); s1.y = __shfl_xor(own.y, 16);
            s1.z = __shfl_xor(own.z, 16); s1.w = __shfl_xor(own.w, 16);
            s2.x = __shfl_xor(own.x, 32); s2.y = __shfl_xor(own.y, 32);
            s2.z = __shfl_xor(own.z, 32); s2.w = __shfl_xor(own.w, 32);
            const float xv[12] = {own.x, own.y, own.z, own.w,
                                  s1.x,  s1.y,  s1.z,  s1.w,
                                  s2.x,  s2.y,  s2.z,  s2.w};
            floatx4 acc0 = {0.f, 0.f, 0.f, 0.f};
            floatx4 acc1 = {0.f, 0.f, 0.f, 0.f};
            acc0 = mfma_bf16(make_afrag<0>(xv), b0, acc0);
            acc1 = mfma_bf16(make_afrag<1>(xv), b1, acc1);
            acc0 = mfma_bf16(make_afrag<2>(xv), b2, acc0);
            acc1 = mfma_bf16(make_afrag<3>(xv), b3, acc1);
            acc0 = mfma_bf16(make_afrag<4>(xv), b4, acc0);
            acc0 = acc0 + acc1;
            tb[(q * 4 + 0) * 20 + n] = acc0[0];
            tb[(q * 4 + 1) * 20 + n] = acc0[1];
            tb[(q * 4 + 2) * 20 + n] = acc0[2];
            tb[(q * 4 + 3) * 20 + n] = acc0[3];
            const float4 o = *reinterpret_cast<const float4*>(
                &tb[(lane >> 2) * 20 + (lane & 3) * 4]);
            *reinterpret_cast<float4*>(out + (size_t)t * 256 + lane * 4) = o;
        }
    }
#undef TILE
#undef PREF
}

extern "C" void kernel_launch(void* const* d_in, const int* in_sizes, int n_in,
                              void* d_out, int out_size, void* d_ws, size_t ws_size,
                              hipStream_t stream) {
    const float* x = (const float*)d_in[0];
    const float* W = (const float*)d_in[1];
    float* out = (float*)d_out;
    const int Bn = in_sizes[0] / 16;   // 1048576
    const int ntiles = Bn >> 4;        // 65536
    // 2048 blocks x 4 waves = 8192 waves; 8 tiles/wave exactly.
    bilinear16_kernel<<<2048, 256, 0, stream>>>(x, W, out, ntiles);
}

// Round 7
// 122.096 us; speedup vs baseline: 1.0173x; 1.0173x over previous
//
#include <hip/hip_runtime.h>
#include <hip/hip_bf16.h>

// out[b,k] = sum_{i,j} x[b,i] * W[k,i,j] * x[b,j]
// GEMM P (B x 160 XOR-classed pair-products) @ Q (160 x 16),
// 5 x mfma_f32_16x16x32_bf16 per 16-row tile.
//
// R12: per-tile VALU diet. Invariant across R5/R7/R9/R10/R11: absolute
// VALU time ~17.8us-equiv (~330 VALU instr/tile vs ~75 essential) while
// every memory-schedule change was neutral -> the bloat is in generated
// scalar code, not the schedule. Changes (all value-safe or sub-ulp):
//   1) bf16 pack via plain bit ops: u += 0x8000 (round-half-away, differs
//      from RNE only on exact 2^-16 ties); (ua>>16)|(ub&0xFFFF0000).
//      <=5 instr/pair guaranteed vs suspected ~12/value soft-RNE from
//      __float22bfloat162_rn.
//   2) readfirstlane(wid): waveId/tile bases provably wave-uniform ->
//      SGPR-base+voffset load/store forms; per-tile addr VALU -> ~0.
//   3) ring swizzle (chunk slot rotated by (row>>1)&3; inverse rotation
//      applied to the global SOURCE address — both sides, rule #21):
//      ds_read conflicts 8-way -> 2-way (free, m136).
//   4) single acc chain (R5-verified order), AGPR-pinned b-frags kept,
//      R11 vmcnt ledger kept VERBATIM (harness-verified):
//      stream L0,L1,[C0 S0 L2]..[C5 S5 L7],[C6 S6],[C7 S7];
//      wait vmcnt(1) at j=0,7; vmcnt(2) at j=1..6 (in-order retirement).
//
// XOR class algebra unchanged (orbit-enumeration verified): K-slot
// k = 32s+8q+j holds, at lane quad q, x[alpha_c^4q]*x[beta_c^4q], c=8s+j;
// 120 off-diag pairs net weight 1, 16 diagonals once. xv slot s = raw
// chunk s^q of row n.

typedef __attribute__((ext_vector_type(8)))  short  short8;
typedef __attribute__((ext_vector_type(8)))  __bf16 bf16x8;
typedef __attribute__((ext_vector_type(4)))  float  floatx4;

#define DEV static __device__ __forceinline__

// ---- XOR class table ----
constexpr int cA(int c) {            // alpha
    if (c < 24) { const int dIdx = c >> 1, v = c & 1;
        const int hi = dIdx / 3, lo = dIdx % 3 + 1;
        const int base = (hi == 3) ? 1 : 0;
        const int l = v ? ((lo == 1) ? 2 : 1) : 0;
        return base * 4 + l; }
    if (c < 36) { const int g = c - 24, hi = g / 4 + 1, l = g & 3;
        const int base = (hi == 3) ? 1 : 0;
        return base * 4 + l; }
    return c - 36;
}
constexpr int cDd(int c) {           // d = alpha ^ beta
    if (c < 24) { const int dIdx = c >> 1;
        return (dIdx / 3) * 4 + (dIdx % 3 + 1); }
    if (c < 36) { return ((c - 24) / 4 + 1) * 4; }
    return 0;
}
constexpr int   cB(int c) { return cA(c) ^ cDd(c); }
constexpr float cW(int c) { return (c >= 24 && c < 36) ? 0.5f : 1.0f; }

template <int C>
DEV float pval(const float* xv) {    // xv indexed directly by value id (<=11)
    return xv[cA(C)] * xv[cB(C)];
}

// bf16 pack, round-half-away (sub-ulp vs RNE), plain bit ops: cheap & exact-
// by-construction (no intrinsic-semantics risk). lo16 of result = a.
DEV unsigned pack_bf16(float a, float b) {
    const unsigned ua = __builtin_bit_cast(unsigned, a) + 0x8000u;
    const unsigned ub = __builtin_bit_cast(unsigned, b) + 0x8000u;
    return (ua >> 16) | (ub & 0xFFFF0000u);
}

template <int S>   // frag S covers classes c = 8S .. 8S+7
DEV short8 make_afrag(const float* xv) {
    union { short8 s; unsigned u[4]; } u;
    u.u[0] = pack_bf16(pval<8 * S + 0>(xv), pval<8 * S + 1>(xv));
    u.u[1] = pack_bf16(pval<8 * S + 2>(xv), pval<8 * S + 3>(xv));
    u.u[2] = pack_bf16(pval<8 * S + 4>(xv), pval<8 * S + 5>(xv));
    u.u[3] = pack_bf16(pval<8 * S + 6>(xv), pval<8 * S + 7>(xv));
    return u.s;
}

DEV floatx4 mfma_bf16(short8 a, short8 b, floatx4 c) {
    return __builtin_amdgcn_mfma_f32_16x16x32_bf16(
        __builtin_bit_cast(bf16x8, a), __builtin_bit_cast(bf16x8, b), c, 0, 0, 0);
}

// ---- Q element for flat slot e = n*160 + k,  k = 32s + 8q + j ----
DEV float q_elem(const float* __restrict__ W, int e) {
    const int n = e / 160;
    const int k = e - n * 160;
    const int s = k >> 5, q = (k >> 3) & 3, j = k & 7;
    const int c = 8 * s + j;
    const int I = cA(c) ^ (q << 2);
    const int J = cB(c) ^ (q << 2);
    return (I == J) ? W[n * 256 + I * 16 + I]
                    : cW(c) * (W[n * 256 + I * 16 + J] + W[n * 256 + J * 16 + I]);
}

typedef const __attribute__((address_space(1))) unsigned char* gptr_t;
typedef       __attribute__((address_space(3))) unsigned char* lptr_t;

__global__ __launch_bounds__(256, 8)
void bilinear16_kernel(const float* __restrict__ x, const float* __restrict__ W,
                       float* __restrict__ out, int ntiles) {
    __shared__ __align__(16) short Qt[16][160];     // 5120 B
    __shared__ __align__(16) float Tb[4][320];      // 5120 B
    __shared__ __align__(16) float Ring[4][2][256]; // 8192 B (per-wave 2x1KB)

    const int tid = threadIdx.x;
    for (int e = tid; e < 16 * 160; e += 256) {
        __hip_bfloat16 h = __float2bfloat16(q_elem(W, e));
        Qt[0][e] = *reinterpret_cast<short*>(&h);
    }
    __syncthreads();

    const int lane = tid & 63;
    const int n    = lane & 15;   // MFMA A-row / C col (fixed by HW layout)
    const int q    = lane >> 4;   // MFMA k-group quad
    // Wave-uniform id as SGPR: makes every tile base provably scalar ->
    // SGPR-base + voffset memory forms, ~zero per-tile address VALU.
    const int wid  = __builtin_amdgcn_readfirstlane(tid >> 6);
    float* const tb   = Tb[wid];
    float* const ring = &Ring[wid][0][0];

    // B-frags (20 regs), resident, pinned to AGPRs (R10-verified).
    short8 b0 = *reinterpret_cast<const short8*>(&Qt[n][0 * 32 + q * 8]);
    short8 b1 = *reinterpret_cast<const short8*>(&Qt[n][1 * 32 + q * 8]);
    short8 b2 = *reinterpret_cast<const short8*>(&Qt[n][2 * 32 + q * 8]);
    short8 b3 = *reinterpret_cast<const short8*>(&Qt[n][3 * 32 + q * 8]);
    short8 b4 = *reinterpret_cast<const short8*>(&Qt[n][4 * 32 + q * 8]);
    asm("" : "+a"(b0)); asm("" : "+a"(b1)); asm("" : "+a"(b2));
    asm("" : "+a"(b3)); asm("" : "+a"(b4));

    const int waveId = blockIdx.x * 4 + wid;      // scalar
    const int nwaves = gridDim.x * 4;             // scalar

    // Ring swizzle: LDS slot (row np, pos sp) holds chunk (sp - rot(np))&3,
    // rot(r) = (r>>1)&3. Linear gload_lds dest (lane*16B) => lane l must
    // SOURCE global chunk cp = ((l&3) - ((l>>3)&3)) & 3 of row l>>2.
    // Read of (row n, chunk c) lands at pos ((c + rot(n)) & 3).
    // Result: ds_read 16-lane groups hit 8 bank-quads x 2 lanes = 2-way (free).
    const int src_off = (lane >> 2) * 16 + ((((lane & 3) - ((lane >> 3) & 3)) & 3) << 2);
    const int rotn = ((lane & 15) >> 1) & 3;
    const int ro0 = n * 16 + (((q       + rotn) & 3) << 2);
    const int ro1 = n * 16 + ((((q ^ 1) + rotn) & 3) << 2);
    const int ro2 = n * 16 + ((((q ^ 2) + rotn) & 3) << 2);

    // Compute+store one tile whose swizzled image sits at ring slot `rs`.
    auto tile_compute = [&](const float* rs, float* obase) {
        const float4 v0 = *reinterpret_cast<const float4*>(rs + ro0);
        const float4 v1 = *reinterpret_cast<const float4*>(rs + ro1);
        const float4 v2 = *reinterpret_cast<const float4*>(rs + ro2);
        const float xv[12] = {v0.x, v0.y, v0.z, v0.w,
                              v1.x, v1.y, v1.z, v1.w,
                              v2.x, v2.y, v2.z, v2.w};
        floatx4 acc = {0.f, 0.f, 0.f, 0.f};
        acc = mfma_bf16(make_afrag<0>(xv), b0, acc);
        acc = mfma_bf16(make_afrag<1>(xv), b1, acc);
        acc = mfma_bf16(make_afrag<2>(xv), b2, acc);
        acc = mfma_bf16(make_afrag<3>(xv), b3, acc);
        acc = mfma_bf16(make_afrag<4>(xv), b4, acc);
        // C/D layout: col = lane&15, row = q*4 + reg [m89-verified].
        tb[(q * 4 + 0) * 20 + n] = acc[0];
        tb[(q * 4 + 1) * 20 + n] = acc[1];
        tb[(q * 4 + 2) * 20 + n] = acc[2];
        tb[(q * 4 + 3) * 20 + n] = acc[3];
        const float4 o = *reinterpret_cast<const float4*>(
            &tb[(lane >> 2) * 20 + (lane & 3) * 4]);
        *reinterpret_cast<float4*>(obase + lane * 4) = o;
    };

#define PREF(J)                                                                  \
    __builtin_amdgcn_global_load_lds(                                            \
        (gptr_t)(const void*)(x + (size_t)(t0 + (J) * nwaves) * 256 + src_off),  \
        (lptr_t)(void*)(ring + ((J) & 1) * 256), 16, 0, 0)

#define TILE(J, VMC)                                                             \
    do {                                                                         \
        asm volatile("s_waitcnt vmcnt(" #VMC ")" ::: "memory");                  \
        tile_compute(ring + ((J) & 1) * 256,                                     \
                     out + (size_t)(t0 + (J) * nwaves) * 256);                   \
        if ((J) < 6) { asm volatile("" ::: "memory"); PREF((J) + 2); }           \
    } while (0)

    if (ntiles == nwaves * 8) {
        const int t0 = waveId;
        PREF(0); PREF(1);
        TILE(0, 1); TILE(1, 2); TILE(2, 2); TILE(3, 2);
        TILE(4, 2); TILE(5, 2); TILE(6, 2); TILE(7, 1);
    } else {
        // Generic fallback (shuffle-based, no pipeline).
        for (int t = waveId; t < ntiles; t += nwaves) {
            const float4 own = *reinterpret_cast<const float4*>(
                x + (size_t)t * 256 + n * 16 + q * 4);
            float4 s1, s2;
            s1.x = __shfl_xor(own.x, 16); s1.y = __shfl_xor(own.y, 16);
            s1.z = __shfl_xor(own.z, 16); s1.w = __shfl_xor(own.w, 16);
            s2.x = __shfl_xor(own.x, 32); s2.y = __shfl_xor(own.y, 32);
            s2.z = __shfl_xor(own.z, 32); s2.w = __shfl_xor(own.w, 32);
            const float xv[12] = {own.x, own.y, own.z, own.w,
                                  s1.x,  s1.y,  s1.z,  s1.w,
                                  s2.x,  s2.y,  s2.z,  s2.w};
            floatx4 acc = {0.f, 0.f, 0.f, 0.f};
            acc = mfma_bf16(make_afrag<0>(xv), b0, acc);
            acc = mfma_bf16(make_afrag<1>(xv), b1, acc);
            acc = mfma_bf16(make_afrag<2>(xv), b2, acc);
            acc = mfma_bf16(make_afrag<3>(xv), b3, acc);
            acc = mfma_bf16(make_afrag<4>(xv), b4, acc);
            tb[(q * 4 + 0) * 20 + n] = acc[0];
            tb[(q * 4 + 1) * 20 + n] = acc[1];
            tb[(q * 4 + 2) * 20 + n] = acc[2];
            tb[(q * 4 + 3) * 20 + n] = acc[3];
            const float4 o = *reinterpret_cast<const float4*>(
                &tb[(lane >> 2) * 20 + (lane & 3) * 4]);
            *reinterpret_cast<float4*>(out + (size_t)t * 256 + lane * 4) = o;
        }
    }
#undef TILE
#undef PREF
}

extern "C" void kernel_launch(void* const* d_in, const int* in_sizes, int n_in,
                              void* d_out, int out_size, void* d_ws, size_t ws_size,
                              hipStream_t stream) {
    const float* x = (const float*)d_in[0];
    const float* W = (const float*)d_in[1];
    float* out = (float*)d_out;
    const int Bn = in_sizes[0] / 16;   // 1048576
    const int ntiles = Bn >> 4;        // 65536
    // 2048 blocks x 4 waves = 8192 waves; 8 tiles/wave exactly.
    bilinear16_kernel<<<2048, 256, 0, stream>>>(x, W, out, ntiles);
}